// Round 9
// baseline (8863.263 us; speedup 1.0000x reference)
//
#include <hip/hip_runtime.h>

typedef _Float16 h2f __attribute__((ext_vector_type(2)));

#define LOG2E 1.44269504088896f

__device__ __forceinline__ float fexp2(float x){ return __builtin_amdgcn_exp2f(x); }
__device__ __forceinline__ float frcp (float x){ return __builtin_amdgcn_rcpf(x); }
__device__ __forceinline__ float sigm (float x){ return frcp(1.f + fexp2(-LOG2E*x)); }
__device__ __forceinline__ float tanhf2(float x){
  x = fminf(15.f, fmaxf(-15.f, x));
  float e = fexp2(2.f*LOG2E*x);
  return (e-1.f)*frcp(e+1.f);
}
__device__ __forceinline__ unsigned pkh2(float a, float b){
  h2f h; h.x = (_Float16)a; h.y = (_Float16)b;
  return __builtin_bit_cast(unsigned, h);
}

#if __has_builtin(__builtin_amdgcn_fdot2)
__device__ __forceinline__ float dot2(unsigned a, unsigned b, float c){
  return __builtin_amdgcn_fdot2(__builtin_bit_cast(h2f,a), __builtin_bit_cast(h2f,b), c, false);
}
#else
__device__ __forceinline__ float dot2(unsigned a, unsigned b, float c){
  h2f ha=__builtin_bit_cast(h2f,a), hb=__builtin_bit_cast(h2f,b);
  return c + (float)ha.x*(float)hb.x + (float)ha.y*(float)hb.y;
}
#endif

__device__ __forceinline__ void dot8_2(uint4 w, uint4 x, float& a0, float& a1){
  a0 = dot2(w.x, x.x, a0); a1 = dot2(w.y, x.y, a1);
  a0 = dot2(w.z, x.z, a0); a1 = dot2(w.w, x.w, a1);
}

// simple matvec
template<int N, int K8>
__device__ __forceinline__ float mv(const uint4* __restrict__ W, const uint4* __restrict__ xs, int n){
  float a0 = 0.f, a1 = 0.f;
  #pragma unroll 4
  for (int k8 = 0; k8 < K8; ++k8)
    dot8_2(W[k8*N + n], xs[k8], a0, a1);
  return a0 + a1;
}

// chunked load-then-compute (R3-proven: call-local, fits 64 VGPR, no spills)
template<int N, int K8, int C>
__device__ __forceinline__ float mvc(const uint4* __restrict__ W, const uint4* __restrict__ xs, int n){
  float a0 = 0.f, a1 = 0.f;
  int k8 = 0;
  #pragma unroll 1
  for (; k8 + C <= K8; k8 += C){
    uint4 w[C];
    #pragma unroll
    for (int i = 0; i < C; ++i) w[i] = W[(size_t)(k8+i)*N + n];
    #pragma unroll
    for (int i = 0; i < C; ++i) dot8_2(w[i], xs[k8+i], a0, a1);
  }
  if constexpr (K8 % C){
    constexpr int R = K8 % C;
    uint4 w[R];
    #pragma unroll
    for (int i = 0; i < R; ++i) w[i] = W[(size_t)(k8+i)*N + n];
    #pragma unroll
    for (int i = 0; i < R; ++i) dot8_2(w[i], xs[k8+i], a0, a1);
  }
  return a0 + a1;
}

// ---------------- workspace layout (bytes) ----------------
static constexpr size_t OFF_W1   = 0;          // 256x400
static constexpr size_t OFF_W2   = 204800;     // 128x256
static constexpr size_t OFF_WIHA = 270336;     // 768x384
static constexpr size_t OFF_WHHA = 860160;     // 768x256
static constexpr size_t OFF_WQ   = 1253376;    // 256x256
static constexpr size_t OFF_WP   = 1384448;    // 256x512
static constexpr size_t OFF_WD1I = 1646592;    // 768x256
static constexpr size_t OFF_WD1H = 2039808;
static constexpr size_t OFF_WD2I = 2433024;
static constexpr size_t OFF_WD2H = 2826240;
static constexpr size_t OFF_WMEL = 3219456;    // 400x256
static constexpr size_t OFF_WM   = 3424256;    // 256x256
static constexpr size_t OFF_TPM  = 3555328;    // tanh(pm) f16 [128][128][512]
static constexpr size_t OFF_ENCH = 37109760;   // enc f16 [128][512][128]

// ---------------- prep kernels ----------------
__global__ void pack_w(const float* __restrict__ src, uint4* __restrict__ dst, int N, int K8){
  int idx = blockIdx.x*blockDim.x + threadIdx.x;
  if (idx >= N*K8) return;
  int n = idx % N, k8 = idx / N;
  const float* s = src + (size_t)n*(K8*8) + k8*8;
  dst[idx] = make_uint4(pkh2(s[0],s[1]), pkh2(s[2],s[3]), pkh2(s[4],s[5]), pkh2(s[6],s[7]));
}

__global__ void conv_enc(const float* __restrict__ enc, unsigned* __restrict__ encH){
  size_t i = blockIdx.x*(size_t)blockDim.x + threadIdx.x;
  if (i >= (size_t)128*512*128) return;
  const float2 f = *(const float2*)(enc + 2*i);
  encH[i] = pkh2(f.x, f.y);
}

__global__ __launch_bounds__(1024) void pm_kernel(const float* __restrict__ enc,
    const uint4* __restrict__ Wmp, unsigned* __restrict__ tpm)
{
  int b = blockIdx.y, tc = blockIdx.x;
  int tid = threadIdx.x;
  __shared__ __align__(16) unsigned s_e[4][128];
  if (tid < 512){
    int r = tid >> 7, d2 = tid & 127;
    const float2 f = *(const float2*)(enc + ((size_t)b*512 + tc*4 + r)*256 + 2*d2);
    s_e[r][d2] = pkh2(f.x, f.y);
  }
  __syncthreads();
  int d = tid & 255, r = tid >> 8;
  float acc = mv<256,32>(Wmp, (const uint4*)s_e[r], d);
  float tq = tanhf2(acc);
  float hi = __shfl_down(tq, 1);
  if ((d & 1) == 0)
    tpm[(size_t)b*65536 + (size_t)(d>>1)*512 + (tc*4 + r)] = pkh2(tq, hi);
}

// Prenet hoisted: pre2(t,b) stashed in the ALIGNMENTS output slot (first 64
// u32 of out_align[b][t]) — decoder reads it at P1(t), softmax overwrites the
// slot later in the same step. Zero extra workspace.
__global__ __launch_bounds__(256) void prenet_kernel(
    const float* __restrict__ inputs,
    const float* __restrict__ b1, const float* __restrict__ b2,
    const uint4* __restrict__ W1p, const uint4* __restrict__ W2p,
    float* __restrict__ out)
{
  int t = blockIdx.x, b = blockIdx.y;   // t = slot (frame t-1; zeros at t=0)
  int tid = threadIdx.x;
  __shared__ __align__(16) unsigned s_x[200];
  __shared__ __align__(16) unsigned s_p1[128];
  __shared__ float s_a[256];
  if (tid < 200){
    unsigned xv = 0u;
    if (t > 0){
      const float2 f = *(const float2*)(inputs + (size_t)b*80000 + (size_t)(t-1)*400 + 2*tid);
      xv = pkh2(f.x, f.y);
    }
    s_x[tid] = xv;
  }
  __syncthreads();
  float a = fmaxf(mv<256,50>(W1p, (const uint4*)s_x, tid) + b1[tid], 0.f);
  s_a[tid] = a;
  __syncthreads();
  if (tid < 128) s_p1[tid] = pkh2(s_a[2*tid], s_a[2*tid+1]);
  __syncthreads();
  if (tid < 128){
    float p = fmaxf(mv<128,32>(W2p, (const uint4*)s_p1, tid) + b2[tid], 0.f);
    float pN = __shfl_down(p, 1);
    if (!(tid & 1)){
      unsigned* dst = (unsigned*)(out + (size_t)10240000 + ((size_t)b*200 + t)*512);
      dst[tid>>1] = pkh2(p, pN);
    }
  }
}

// Mel hoisted: decoder stored packed dec_in (128 u32) at out_mel[b][t][0:128];
// this kernel reads it, then overwrites the slot with the 400 mel floats.
__global__ __launch_bounds__(512) void mel_kernel(
    const float* __restrict__ bmel, const uint4* __restrict__ Wmelp,
    float* __restrict__ out)
{
  int t = blockIdx.x, b = blockIdx.y;
  int tid = threadIdx.x;
  __shared__ __align__(16) unsigned s_d[128];
  float* po = out + ((size_t)b*200 + t)*400;
  if (tid < 128) s_d[tid] = ((const unsigned*)po)[tid];
  __syncthreads();
  if (tid < 400){
    float r = mvc<400,32,8>(Wmelp, (const uint4*)s_d, tid) + bmel[tid];
    __builtin_nontemporal_store(r, &po[tid]);
  }
}

// ---------------- decoder ----------------
// Designed to fit the allocator's 64-VGPR target (R3-proven shape): all
// chunk buffers call-local, C<=8, no register state carried across barriers
// (except softmax's single float). (1024,1) is a free observation on the cap.
__global__ __launch_bounds__(1024, 1) void decoder(
   const float* __restrict__ biha, const float* __restrict__ bhha,
   const float* __restrict__ vvec, const float* __restrict__ bp,
   const float* __restrict__ bd1i, const float* __restrict__ bd1h,
   const float* __restrict__ bd2i, const float* __restrict__ bd2h,
   const uint4* __restrict__ Wihap, const uint4* __restrict__ Whhap,
   const uint4* __restrict__ Wqp, const uint4* __restrict__ Wpp,
   const uint4* __restrict__ Wd1ip, const uint4* __restrict__ Wd1hp,
   const uint4* __restrict__ Wd2ip, const uint4* __restrict__ Wd2hp,
   const unsigned* __restrict__ tpm, const unsigned* __restrict__ encH,
   float* __restrict__ out)
{
  const int tid = threadIdx.x;
  const int b = blockIdx.x;

  __shared__ __align__(16) unsigned s_cin2[192]; // [pre2(64) | ctx(128)]
  __shared__ __align__(16) unsigned s_cat2[256]; // [attn_h(128) | ctx(128)]
  __shared__ __align__(16) unsigned s_di2[128];  // dec_in packed
  __shared__ __align__(16) unsigned s_h12[128];
  __shared__ __align__(16) unsigned s_h22[128];
  __shared__ float  s_gha[768], s_gh1[768], s_gh2[768];
  __shared__ float  s_g[768];
  __shared__ float  s_ahf[256], s_h1f[256], s_h2f[256];
  __shared__ float  s_dif[256];
  __shared__ float4 s_tv[128];      // {tanhq[2d2], tanhq[2d2+1], v[2d2], v[2d2+1]}
  __shared__ float  s_lp[2][512];
  __shared__ float2 s_cp[8][128];
  __shared__ float  s_mvp[4][256];
  __shared__ float  s_align[512];
  __shared__ float  s_red[16];

  if (tid < 192) s_cin2[tid] = 0u;
  if (tid < 256){ s_cat2[tid]=0u; s_ahf[tid]=0.f; s_h1f[tid]=0.f; s_h2f[tid]=0.f; }
  if (tid < 128){ s_h12[tid]=0u; s_h22[tid]=0u;
                  s_tv[tid].z = vvec[2*tid]; s_tv[tid].w = vvec[2*tid+1]; }
  __syncthreads();

  const unsigned* tpmB = tpm  + (size_t)b*65536;
  const unsigned* encB = encH + (size_t)b*65536;
  float* outMel = out + (size_t)b*200*400;
  float* outAl  = out + (size_t)10240000 + (size_t)b*200*512;

  for (int t = 0; t < 200; ++t){
    // ===== P1: gha[768] || gh2 rows 0..191 || pre2 load (64)
    if (tid < 768){
      s_gha[tid] = mvc<768,32,8>(Whhap, (const uint4*)s_cat2, tid) + bhha[tid];
    } else if (tid < 960){
      int r = tid - 768;
      s_gh2[r] = mvc<768,32,8>(Wd2hp, (const uint4*)s_h22, r) + bd2h[r];
    } else {
      s_cin2[tid-960] = ((const unsigned*)(outAl + (size_t)t*512))[tid-960];
    }
    __syncthreads();
    // ===== P2: gh1[768] || gh2 rows 192..447
    if (tid < 768){
      s_gh1[tid] = mvc<768,32,8>(Wd1hp, (const uint4*)s_h12, tid) + bd1h[tid];
    } else {
      int r = 192 + tid - 768;
      s_gh2[r] = mvc<768,32,8>(Wd2hp, (const uint4*)s_h22, r) + bd2h[r];
    }
    __syncthreads();
    // ===== P3: gi_a[768] (K=384) || gh2 rows 448..703
    if (tid < 768){
      float gi = mvc<768,48,8>(Wihap, (const uint4*)s_cin2, tid) + biha[tid];
      s_g[tid] = (tid < 512) ? sigm(gi + s_gha[tid]) : gi;
    } else {
      int r = 448 + tid - 768;
      s_gh2[r] = mvc<768,32,8>(Wd2hp, (const uint4*)s_h22, r) + bd2h[r];
    }
    __syncthreads();
    // ===== GA: attn-GRU gates (256) || gh2 rows 704..767 (64)
    if (tid < 256){
      float rr = s_g[tid], z = s_g[256+tid];
      float nv = tanhf2(s_g[512+tid] + rr*s_gha[512+tid]);
      float h  = nv + z*(s_ahf[tid] - nv);
      s_ahf[tid] = h;
      float hN = __shfl_down(h, 1);
      if (!(tid&1)) s_cat2[tid>>1] = pkh2(h, hN);
    } else if (tid < 320){
      int r = 704 + tid - 256;
      s_gh2[r] = mvc<768,32,8>(Wd2hp, (const uint4*)s_h22, r) + bd2h[r];
    }
    __syncthreads();
    // ===== P4: q = Wq@attn_h (split-K2, 512 threads)
    if (tid < 512){
      int n = tid & 255, p = tid >> 8;
      s_mvp[p][n] = mvc<256,16,8>(Wqp + (size_t)p*16*256, (const uint4*)s_cat2 + p*16, n);
    }
    __syncthreads();
    // ===== QT: tanh(q)
    if (tid < 256){
      float q = s_mvp[0][tid] + s_mvp[1][tid];
      ((float*)&s_tv[tid>>1])[tid&1] = tanhf2(q);
    }
    __syncthreads();
    // ===== P5: logits via tanh-sum identity (1024, nt streams, 16-wide)
    {
      int tt = tid & 511, dh = tid >> 9;
      const unsigned* tp = tpmB + tt + (size_t)dh*32768;
      float acc = 0.f;
      #pragma unroll 1
      for (int c = 0; c < 64; c += 16){
        unsigned tw[16];
        #pragma unroll
        for (int i = 0; i < 16; ++i) tw[i] = __builtin_nontemporal_load(&tp[(size_t)(c+i)*512]);
        #pragma unroll
        for (int i = 0; i < 16; ++i){
          h2f ta = __builtin_bit_cast(h2f, tw[i]);
          float4 tv = s_tv[dh*64 + c + i];
          float ta0 = (float)ta.x, ta1 = (float)ta.y;
          acc += tv.z*(ta0+tv.x)*frcp(1.f+ta0*tv.x)
               + tv.w*(ta1+tv.y)*frcp(1.f+ta1*tv.y);
        }
      }
      s_lp[dh][tt] = acc;
    }
    __syncthreads();
    // ===== softmax, NO max pass (|logit| <= sum|v| ~ 10.2, f32 exp safe)
    float ee = 0.f;
    if (tid < 512){
      float lg = s_lp[0][tid] + s_lp[1][tid];
      ee = fexp2(LOG2E*lg);
      float s = ee;
      #pragma unroll
      for (int off = 32; off >= 1; off >>= 1) s += __shfl_xor(s, off);
      if ((tid & 63) == 0) s_red[tid>>6] = s;
    }
    __syncthreads();
    if (tid < 512){
      float S = (s_red[0]+s_red[1])+(s_red[2]+s_red[3])
              + (s_red[4]+s_red[5])+(s_red[6]+s_red[7]);
      float a = ee * frcp(S);
      s_align[tid] = a;
      __builtin_nontemporal_store(a, &outAl[(size_t)t*512 + tid]);
    }
    __syncthreads();
    // ===== P6: ctx partials (1024, nt streams, 16-wide)
    {
      int d2 = tid & 127, tc = tid >> 7;
      const unsigned* eb = encB + d2 + (size_t)tc*8192;
      float ax = 0.f, ay = 0.f;
      #pragma unroll 1
      for (int c = 0; c < 64; c += 16){
        unsigned ew[16];
        #pragma unroll
        for (int i = 0; i < 16; ++i) ew[i] = __builtin_nontemporal_load(&eb[(size_t)(c+i)*128]);
        #pragma unroll
        for (int i = 0; i < 16; ++i){
          float a = s_align[tc*64 + c + i];
          h2f e2 = __builtin_bit_cast(h2f, ew[i]);
          ax += a*(float)e2.x; ay += a*(float)e2.y;
        }
      }
      s_cp[tc][d2] = make_float2(ax, ay);
    }
    __syncthreads();
    // ===== CR: ctx reduce + pack
    if (tid < 256){
      const float* cp = (const float*)s_cp;
      float c = 0.f;
      #pragma unroll
      for (int k = 0; k < 8; ++k) c += cp[k*256 + tid];
      float cN = __shfl_down(c, 1);
      if (!(tid&1)){ unsigned pk = pkh2(c, cN); s_cin2[64+(tid>>1)] = pk; s_cat2[128+(tid>>1)] = pk; }
    }
    __syncthreads();
    // ===== P7: dec_in = Wp@cat(attn_h,ctx) (split-K4, 1024)
    {
      int n = tid & 255, p = tid >> 8;
      s_mvp[p][n] = mvc<256,16,8>(Wpp + (size_t)p*16*256, (const uint4*)s_cat2 + p*16, n);
    }
    __syncthreads();
    // ===== DM
    if (tid < 256){
      float di = s_mvp[0][tid]+s_mvp[1][tid]+s_mvp[2][tid]+s_mvp[3][tid] + bp[tid];
      s_dif[tid] = di;
      float dN = __shfl_down(di, 1);
      if (!(tid&1)) s_di2[tid>>1] = pkh2(di, dN);
    }
    __syncthreads();
    // ===== P8: gi_d1 (768)
    if (tid < 768){
      float gi = mvc<768,32,8>(Wd1ip, (const uint4*)s_di2, tid) + bd1i[tid];
      s_g[tid] = (tid < 512) ? sigm(gi + s_gh1[tid]) : gi;
    }
    __syncthreads();
    // ===== G1
    if (tid < 256){
      float rr = s_g[tid], z = s_g[256+tid];
      float nv = tanhf2(s_g[512+tid] + rr*s_gh1[512+tid]);
      float h  = nv + z*(s_h1f[tid] - nv);
      s_h1f[tid] = h;
      float di = s_dif[tid] + h; s_dif[tid] = di;
      float hN = __shfl_down(h, 1), dN = __shfl_down(di, 1);
      if (!(tid&1)){ s_h12[tid>>1] = pkh2(h, hN); s_di2[tid>>1] = pkh2(di, dN); }
    }
    __syncthreads();
    // ===== P9: gi_d2 (768)
    if (tid < 768){
      float gi = mvc<768,32,8>(Wd2ip, (const uint4*)s_di2, tid) + bd2i[tid];
      s_g[tid] = (tid < 512) ? sigm(gi + s_gh2[tid]) : gi;
    }
    __syncthreads();
    // ===== G2 (+ store packed dec_in for the mel post-kernel)
    if (tid < 256){
      float rr = s_g[tid], z = s_g[256+tid];
      float nv = tanhf2(s_g[512+tid] + rr*s_gh2[512+tid]);
      float h  = nv + z*(s_h2f[tid] - nv);
      s_h2f[tid] = h;
      float di = s_dif[tid] + h;
      float hN = __shfl_down(h, 1), dN = __shfl_down(di, 1);
      if (!(tid&1)){
        unsigned dpk = pkh2(di, dN);
        s_h22[tid>>1] = pkh2(h, hN);
        s_di2[tid>>1] = dpk;   // not needed next phase, kept for symmetry
        ((unsigned*)(outMel + (size_t)t*400))[tid>>1] = dpk;
      }
    }
    __syncthreads();
  }
}

// ---------------- launch ----------------
extern "C" void kernel_launch(void* const* d_in, const int* in_sizes, int n_in,
                              void* d_out, int out_size, void* d_ws, size_t ws_size,
                              hipStream_t stream){
  (void)in_sizes; (void)n_in; (void)out_size; (void)ws_size;
  const float* enc    = (const float*)d_in[0];
  const float* inputs = (const float*)d_in[1];
  const float* W1 = (const float*)d_in[2];   const float* b1 = (const float*)d_in[3];
  const float* W2 = (const float*)d_in[4];   const float* b2 = (const float*)d_in[5];
  const float* Wiha = (const float*)d_in[6]; const float* Whha = (const float*)d_in[7];
  const float* biha = (const float*)d_in[8]; const float* bhha = (const float*)d_in[9];
  const float* Wq = (const float*)d_in[10];  const float* v  = (const float*)d_in[11];
  const float* Wm = (const float*)d_in[12];
  const float* Wp = (const float*)d_in[13];  const float* bp = (const float*)d_in[14];
  const float* Wd1i = (const float*)d_in[15]; const float* Wd1h = (const float*)d_in[16];
  const float* bd1i = (const float*)d_in[17]; const float* bd1h = (const float*)d_in[18];
  const float* Wd2i = (const float*)d_in[19]; const float* Wd2h = (const float*)d_in[20];
  const float* bd2i = (const float*)d_in[21]; const float* bd2h = (const float*)d_in[22];
  const float* Wmel = (const float*)d_in[23]; const float* bmel = (const float*)d_in[24];

  char* ws = (char*)d_ws;
  uint4* W1p   = (uint4*)(ws + OFF_W1);
  uint4* W2p   = (uint4*)(ws + OFF_W2);
  uint4* Wihap = (uint4*)(ws + OFF_WIHA);
  uint4* Whhap = (uint4*)(ws + OFF_WHHA);
  uint4* Wqp   = (uint4*)(ws + OFF_WQ);
  uint4* Wpp   = (uint4*)(ws + OFF_WP);
  uint4* Wd1ip = (uint4*)(ws + OFF_WD1I);
  uint4* Wd1hp = (uint4*)(ws + OFF_WD1H);
  uint4* Wd2ip = (uint4*)(ws + OFF_WD2I);
  uint4* Wd2hp = (uint4*)(ws + OFF_WD2H);
  uint4* Wmelp = (uint4*)(ws + OFF_WMEL);
  uint4* Wmp   = (uint4*)(ws + OFF_WM);
  unsigned* tpm  = (unsigned*)(ws + OFF_TPM);
  unsigned* encH = (unsigned*)(ws + OFF_ENCH);

  auto P = [&](const float* s, uint4* dst, int N, int K){
    int k8 = K/8, tot = N*k8;
    pack_w<<<(tot+255)/256, 256, 0, stream>>>(s, dst, N, k8);
  };
  P(W1, W1p, 256, 400);   P(W2, W2p, 128, 256);
  P(Wiha, Wihap, 768, 384); P(Whha, Whhap, 768, 256);
  P(Wq, Wqp, 256, 256);   P(Wm, Wmp, 256, 256);
  P(Wp, Wpp, 256, 512);
  P(Wd1i, Wd1ip, 768, 256); P(Wd1h, Wd1hp, 768, 256);
  P(Wd2i, Wd2ip, 768, 256); P(Wd2h, Wd2hp, 768, 256);
  P(Wmel, Wmelp, 400, 256);

  conv_enc<<<32768, 256, 0, stream>>>(enc, encH);
  pm_kernel<<<dim3(128,128), 1024, 0, stream>>>(enc, Wmp, tpm);
  prenet_kernel<<<dim3(200,128), 256, 0, stream>>>(inputs, b1, b2, W1p, W2p, (float*)d_out);

  decoder<<<128, 1024, 0, stream>>>(
      biha, bhha, v, bp, bd1i, bd1h, bd2i, bd2h,
      Wihap, Whhap, Wqp, Wpp, Wd1ip, Wd1hp, Wd2ip, Wd2hp,
      tpm, encH, (float*)d_out);

  mel_kernel<<<dim3(200,128), 512, 0, stream>>>(bmel, Wmelp, (float*)d_out);
}

// Round 10
// 8836.382 us; speedup vs baseline: 1.0030x; 1.0030x over previous
//
#include <hip/hip_runtime.h>

typedef _Float16 h2f __attribute__((ext_vector_type(2)));

#define LOG2E 1.44269504088896f

__device__ __forceinline__ float fexp2(float x){ return __builtin_amdgcn_exp2f(x); }
__device__ __forceinline__ float frcp (float x){ return __builtin_amdgcn_rcpf(x); }
__device__ __forceinline__ float sigm (float x){ return frcp(1.f + fexp2(-LOG2E*x)); }
__device__ __forceinline__ float tanhf2(float x){
  x = fminf(15.f, fmaxf(-15.f, x));
  float e = fexp2(2.f*LOG2E*x);
  return (e-1.f)*frcp(e+1.f);
}
__device__ __forceinline__ unsigned pkh2(float a, float b){
  h2f h; h.x = (_Float16)a; h.y = (_Float16)b;
  return __builtin_bit_cast(unsigned, h);
}

#if __has_builtin(__builtin_amdgcn_fdot2)
__device__ __forceinline__ float dot2(unsigned a, unsigned b, float c){
  return __builtin_amdgcn_fdot2(__builtin_bit_cast(h2f,a), __builtin_bit_cast(h2f,b), c, false);
}
#else
__device__ __forceinline__ float dot2(unsigned a, unsigned b, float c){
  h2f ha=__builtin_bit_cast(h2f,a), hb=__builtin_bit_cast(h2f,b);
  return c + (float)ha.x*(float)hb.x + (float)ha.y*(float)hb.y;
}
#endif

__device__ __forceinline__ void dot8_2(uint4 w, uint4 x, float& a0, float& a1){
  a0 = dot2(w.x, x.x, a0); a1 = dot2(w.y, x.y, a1);
  a0 = dot2(w.z, x.z, a0); a1 = dot2(w.w, x.w, a1);
}

// simple matvec
template<int N, int K8>
__device__ __forceinline__ float mv(const uint4* __restrict__ W, const uint4* __restrict__ xs, int n){
  float a0 = 0.f, a1 = 0.f;
  #pragma unroll 4
  for (int k8 = 0; k8 < K8; ++k8)
    dot8_2(W[k8*N + n], xs[k8], a0, a1);
  return a0 + a1;
}

// chunked load-then-compute (R3-proven: call-local, fits 64 VGPR, no spills)
template<int N, int K8, int C>
__device__ __forceinline__ float mvc(const uint4* __restrict__ W, const uint4* __restrict__ xs, int n){
  float a0 = 0.f, a1 = 0.f;
  int k8 = 0;
  #pragma unroll 1
  for (; k8 + C <= K8; k8 += C){
    uint4 w[C];
    #pragma unroll
    for (int i = 0; i < C; ++i) w[i] = W[(size_t)(k8+i)*N + n];
    #pragma unroll
    for (int i = 0; i < C; ++i) dot8_2(w[i], xs[k8+i], a0, a1);
  }
  if constexpr (K8 % C){
    constexpr int R = K8 % C;
    uint4 w[R];
    #pragma unroll
    for (int i = 0; i < R; ++i) w[i] = W[(size_t)(k8+i)*N + n];
    #pragma unroll
    for (int i = 0; i < R; ++i) dot8_2(w[i], xs[k8+i], a0, a1);
  }
  return a0 + a1;
}

// ---------------- workspace layout (bytes) ----------------
static constexpr size_t OFF_W1   = 0;          // 256x400
static constexpr size_t OFF_W2   = 204800;     // 128x256
static constexpr size_t OFF_WIHA = 270336;     // 768x384
static constexpr size_t OFF_WHHA = 860160;     // 768x256
static constexpr size_t OFF_WQ   = 1253376;    // 256x256
static constexpr size_t OFF_WP   = 1384448;    // 256x512
static constexpr size_t OFF_WD1I = 1646592;    // 768x256
static constexpr size_t OFF_WD1H = 2039808;
static constexpr size_t OFF_WD2I = 2433024;
static constexpr size_t OFF_WD2H = 2826240;
static constexpr size_t OFF_WMEL = 3219456;    // 400x256
static constexpr size_t OFF_WM   = 3424256;    // 256x256
static constexpr size_t OFF_TPM  = 3555328;    // tanh(pm) f16 [128][128][512]
static constexpr size_t OFF_ENCH = 37109760;   // enc f16 [128][512][128]

// ---------------- prep kernels ----------------
__global__ void pack_w(const float* __restrict__ src, uint4* __restrict__ dst, int N, int K8){
  int idx = blockIdx.x*blockDim.x + threadIdx.x;
  if (idx >= N*K8) return;
  int n = idx % N, k8 = idx / N;
  const float* s = src + (size_t)n*(K8*8) + k8*8;
  dst[idx] = make_uint4(pkh2(s[0],s[1]), pkh2(s[2],s[3]), pkh2(s[4],s[5]), pkh2(s[6],s[7]));
}

__global__ void conv_enc(const float* __restrict__ enc, unsigned* __restrict__ encH){
  size_t i = blockIdx.x*(size_t)blockDim.x + threadIdx.x;
  if (i >= (size_t)128*512*128) return;
  const float2 f = *(const float2*)(enc + 2*i);
  encH[i] = pkh2(f.x, f.y);
}

__global__ __launch_bounds__(1024) void pm_kernel(const float* __restrict__ enc,
    const uint4* __restrict__ Wmp, unsigned* __restrict__ tpm)
{
  int b = blockIdx.y, tc = blockIdx.x;
  int tid = threadIdx.x;
  __shared__ __align__(16) unsigned s_e[4][128];
  if (tid < 512){
    int r = tid >> 7, d2 = tid & 127;
    const float2 f = *(const float2*)(enc + ((size_t)b*512 + tc*4 + r)*256 + 2*d2);
    s_e[r][d2] = pkh2(f.x, f.y);
  }
  __syncthreads();
  int d = tid & 255, r = tid >> 8;
  float acc = mv<256,32>(Wmp, (const uint4*)s_e[r], d);
  float tq = tanhf2(acc);
  float hi = __shfl_down(tq, 1);
  if ((d & 1) == 0)
    tpm[(size_t)b*65536 + (size_t)(d>>1)*512 + (tc*4 + r)] = pkh2(tq, hi);
}

// Prenet hoisted: pre2(t,b) stashed in the ALIGNMENTS output slot (first 64
// u32 of out_align[b][t]) — decoder reads it at P1(t), softmax overwrites the
// slot later in the same step. Zero extra workspace.
__global__ __launch_bounds__(256) void prenet_kernel(
    const float* __restrict__ inputs,
    const float* __restrict__ b1, const float* __restrict__ b2,
    const uint4* __restrict__ W1p, const uint4* __restrict__ W2p,
    float* __restrict__ out)
{
  int t = blockIdx.x, b = blockIdx.y;   // t = slot (frame t-1; zeros at t=0)
  int tid = threadIdx.x;
  __shared__ __align__(16) unsigned s_x[200];
  __shared__ __align__(16) unsigned s_p1[128];
  __shared__ float s_a[256];
  if (tid < 200){
    unsigned xv = 0u;
    if (t > 0){
      const float2 f = *(const float2*)(inputs + (size_t)b*80000 + (size_t)(t-1)*400 + 2*tid);
      xv = pkh2(f.x, f.y);
    }
    s_x[tid] = xv;
  }
  __syncthreads();
  float a = fmaxf(mv<256,50>(W1p, (const uint4*)s_x, tid) + b1[tid], 0.f);
  s_a[tid] = a;
  __syncthreads();
  if (tid < 128) s_p1[tid] = pkh2(s_a[2*tid], s_a[2*tid+1]);
  __syncthreads();
  if (tid < 128){
    float p = fmaxf(mv<128,32>(W2p, (const uint4*)s_p1, tid) + b2[tid], 0.f);
    float pN = __shfl_down(p, 1);
    if (!(tid & 1)){
      unsigned* dst = (unsigned*)(out + (size_t)10240000 + ((size_t)b*200 + t)*512);
      dst[tid>>1] = pkh2(p, pN);
    }
  }
}

// Mel hoisted: decoder stored packed dec_in (128 u32) at out_mel[b][t][0:128];
// this kernel reads it, then overwrites the slot with the 400 mel floats.
__global__ __launch_bounds__(512) void mel_kernel(
    const float* __restrict__ bmel, const uint4* __restrict__ Wmelp,
    float* __restrict__ out)
{
  int t = blockIdx.x, b = blockIdx.y;
  int tid = threadIdx.x;
  __shared__ __align__(16) unsigned s_d[128];
  float* po = out + ((size_t)b*200 + t)*400;
  if (tid < 128) s_d[tid] = ((const unsigned*)po)[tid];
  __syncthreads();
  if (tid < 400){
    float r = mvc<400,32,8>(Wmelp, (const uint4*)s_d, tid) + bmel[tid];
    __builtin_nontemporal_store(r, &po[tid]);
  }
}

// ---------------- decoder ----------------
// Designed to fit the allocator's 64-VGPR target (R3-proven shape): all
// chunk buffers call-local, C<=8, no register state carried across barriers
// (except softmax's single float). (1024,1) is a free observation on the cap.
__global__ __launch_bounds__(1024, 1) void decoder(
   const float* __restrict__ biha, const float* __restrict__ bhha,
   const float* __restrict__ vvec, const float* __restrict__ bp,
   const float* __restrict__ bd1i, const float* __restrict__ bd1h,
   const float* __restrict__ bd2i, const float* __restrict__ bd2h,
   const uint4* __restrict__ Wihap, const uint4* __restrict__ Whhap,
   const uint4* __restrict__ Wqp, const uint4* __restrict__ Wpp,
   const uint4* __restrict__ Wd1ip, const uint4* __restrict__ Wd1hp,
   const uint4* __restrict__ Wd2ip, const uint4* __restrict__ Wd2hp,
   const unsigned* __restrict__ tpm, const unsigned* __restrict__ encH,
   float* __restrict__ out)
{
  const int tid = threadIdx.x;
  const int b = blockIdx.x;

  __shared__ __align__(16) unsigned s_cin2[192]; // [pre2(64) | ctx(128)]
  __shared__ __align__(16) unsigned s_cat2[256]; // [attn_h(128) | ctx(128)]
  __shared__ __align__(16) unsigned s_di2[128];  // dec_in packed
  __shared__ __align__(16) unsigned s_h12[128];
  __shared__ __align__(16) unsigned s_h22[128];
  __shared__ float  s_gha[768], s_gh1[768], s_gh2[768];
  __shared__ float  s_g[768];
  __shared__ float  s_ahf[256], s_h1f[256], s_h2f[256];
  __shared__ float  s_dif[256];
  __shared__ float4 s_tv[128];      // {tanhq[2d2], tanhq[2d2+1], v[2d2], v[2d2+1]}
  __shared__ float  s_lp[2][512];
  __shared__ float2 s_cp[8][128];
  __shared__ float  s_mvp[4][256];
  __shared__ float  s_align[512];
  __shared__ float  s_red[16];

  if (tid < 192) s_cin2[tid] = 0u;
  if (tid < 256){ s_cat2[tid]=0u; s_ahf[tid]=0.f; s_h1f[tid]=0.f; s_h2f[tid]=0.f; }
  if (tid < 128){ s_h12[tid]=0u; s_h22[tid]=0u;
                  s_tv[tid].z = vvec[2*tid]; s_tv[tid].w = vvec[2*tid+1]; }
  __syncthreads();

  const unsigned* tpmB = tpm  + (size_t)b*65536;
  const unsigned* encB = encH + (size_t)b*65536;
  float* outMel = out + (size_t)b*200*400;
  float* outAl  = out + (size_t)10240000 + (size_t)b*200*512;

  for (int t = 0; t < 200; ++t){
    // ===== P1: gha[768] || gh2 rows 0..191 || pre2 load (64)
    if (tid < 768){
      s_gha[tid] = mvc<768,32,8>(Whhap, (const uint4*)s_cat2, tid) + bhha[tid];
    } else if (tid < 960){
      int r = tid - 768;
      s_gh2[r] = mvc<768,32,8>(Wd2hp, (const uint4*)s_h22, r) + bd2h[r];
    } else {
      s_cin2[tid-960] = ((const unsigned*)(outAl + (size_t)t*512))[tid-960];
    }
    __syncthreads();
    // ===== P2: gh1[768] || gh2 rows 192..447
    if (tid < 768){
      s_gh1[tid] = mvc<768,32,8>(Wd1hp, (const uint4*)s_h12, tid) + bd1h[tid];
    } else {
      int r = 192 + tid - 768;
      s_gh2[r] = mvc<768,32,8>(Wd2hp, (const uint4*)s_h22, r) + bd2h[r];
    }
    __syncthreads();
    // ===== P3: gi_a[768] (K=384) || gh2 rows 448..703
    if (tid < 768){
      float gi = mvc<768,48,8>(Wihap, (const uint4*)s_cin2, tid) + biha[tid];
      s_g[tid] = (tid < 512) ? sigm(gi + s_gha[tid]) : gi;
    } else {
      int r = 448 + tid - 768;
      s_gh2[r] = mvc<768,32,8>(Wd2hp, (const uint4*)s_h22, r) + bd2h[r];
    }
    __syncthreads();
    // ===== GA: attn-GRU gates (256) || gh2 rows 704..767 (64)
    if (tid < 256){
      float rr = s_g[tid], z = s_g[256+tid];
      float nv = tanhf2(s_g[512+tid] + rr*s_gha[512+tid]);
      float h  = nv + z*(s_ahf[tid] - nv);
      s_ahf[tid] = h;
      float hN = __shfl_down(h, 1);
      if (!(tid&1)) s_cat2[tid>>1] = pkh2(h, hN);
    } else if (tid < 320){
      int r = 704 + tid - 256;
      s_gh2[r] = mvc<768,32,8>(Wd2hp, (const uint4*)s_h22, r) + bd2h[r];
    }
    __syncthreads();
    // ===== P4: q = Wq@attn_h (split-K2, 512 threads)
    if (tid < 512){
      int n = tid & 255, p = tid >> 8;
      s_mvp[p][n] = mvc<256,16,8>(Wqp + (size_t)p*16*256, (const uint4*)s_cat2 + p*16, n);
    }
    __syncthreads();
    // ===== QT: tanh(q)
    if (tid < 256){
      float q = s_mvp[0][tid] + s_mvp[1][tid];
      ((float*)&s_tv[tid>>1])[tid&1] = tanhf2(q);
    }
    __syncthreads();
    // ===== P5: logits via tanh-sum identity (1024, nt streams, 16-wide)
    {
      int tt = tid & 511, dh = tid >> 9;
      const unsigned* tp = tpmB + tt + (size_t)dh*32768;
      float acc = 0.f;
      #pragma unroll 1
      for (int c = 0; c < 64; c += 16){
        unsigned tw[16];
        #pragma unroll
        for (int i = 0; i < 16; ++i) tw[i] = __builtin_nontemporal_load(&tp[(size_t)(c+i)*512]);
        #pragma unroll
        for (int i = 0; i < 16; ++i){
          h2f ta = __builtin_bit_cast(h2f, tw[i]);
          float4 tv = s_tv[dh*64 + c + i];
          float ta0 = (float)ta.x, ta1 = (float)ta.y;
          acc += tv.z*(ta0+tv.x)*frcp(1.f+ta0*tv.x)
               + tv.w*(ta1+tv.y)*frcp(1.f+ta1*tv.y);
        }
      }
      s_lp[dh][tt] = acc;
    }
    __syncthreads();
    // ===== softmax, NO max pass (|logit| <= sum|v| ~ 10.2, f32 exp safe)
    float ee = 0.f;
    if (tid < 512){
      float lg = s_lp[0][tid] + s_lp[1][tid];
      ee = fexp2(LOG2E*lg);
      float s = ee;
      #pragma unroll
      for (int off = 32; off >= 1; off >>= 1) s += __shfl_xor(s, off);
      if ((tid & 63) == 0) s_red[tid>>6] = s;
    }
    __syncthreads();
    if (tid < 512){
      float S = (s_red[0]+s_red[1])+(s_red[2]+s_red[3])
              + (s_red[4]+s_red[5])+(s_red[6]+s_red[7]);
      float a = ee * frcp(S);
      s_align[tid] = a;
      __builtin_nontemporal_store(a, &outAl[(size_t)t*512 + tid]);
    }
    __syncthreads();
    // ===== P6: ctx partials (1024, nt streams, 16-wide)
    {
      int d2 = tid & 127, tc = tid >> 7;
      const unsigned* eb = encB + d2 + (size_t)tc*8192;
      float ax = 0.f, ay = 0.f;
      #pragma unroll 1
      for (int c = 0; c < 64; c += 16){
        unsigned ew[16];
        #pragma unroll
        for (int i = 0; i < 16; ++i) ew[i] = __builtin_nontemporal_load(&eb[(size_t)(c+i)*128]);
        #pragma unroll
        for (int i = 0; i < 16; ++i){
          float a = s_align[tc*64 + c + i];
          h2f e2 = __builtin_bit_cast(h2f, ew[i]);
          ax += a*(float)e2.x; ay += a*(float)e2.y;
        }
      }
      s_cp[tc][d2] = make_float2(ax, ay);
    }
    __syncthreads();
    // ===== CR: ctx reduce + pack
    if (tid < 256){
      const float* cp = (const float*)s_cp;
      float c = 0.f;
      #pragma unroll
      for (int k = 0; k < 8; ++k) c += cp[k*256 + tid];
      float cN = __shfl_down(c, 1);
      if (!(tid&1)){ unsigned pk = pkh2(c, cN); s_cin2[64+(tid>>1)] = pk; s_cat2[128+(tid>>1)] = pk; }
    }
    __syncthreads();
    // ===== P7: dec_in = Wp@cat(attn_h,ctx) (split-K4, 1024)
    {
      int n = tid & 255, p = tid >> 8;
      s_mvp[p][n] = mvc<256,16,8>(Wpp + (size_t)p*16*256, (const uint4*)s_cat2 + p*16, n);
    }
    __syncthreads();
    // ===== DM
    if (tid < 256){
      float di = s_mvp[0][tid]+s_mvp[1][tid]+s_mvp[2][tid]+s_mvp[3][tid] + bp[tid];
      s_dif[tid] = di;
      float dN = __shfl_down(di, 1);
      if (!(tid&1)) s_di2[tid>>1] = pkh2(di, dN);
    }
    __syncthreads();
    // ===== P8: gi_d1 (768)
    if (tid < 768){
      float gi = mvc<768,32,8>(Wd1ip, (const uint4*)s_di2, tid) + bd1i[tid];
      s_g[tid] = (tid < 512) ? sigm(gi + s_gh1[tid]) : gi;
    }
    __syncthreads();
    // ===== G1
    if (tid < 256){
      float rr = s_g[tid], z = s_g[256+tid];
      float nv = tanhf2(s_g[512+tid] + rr*s_gh1[512+tid]);
      float h  = nv + z*(s_h1f[tid] - nv);
      s_h1f[tid] = h;
      float di = s_dif[tid] + h; s_dif[tid] = di;
      float hN = __shfl_down(h, 1), dN = __shfl_down(di, 1);
      if (!(tid&1)){ s_h12[tid>>1] = pkh2(h, hN); s_di2[tid>>1] = pkh2(di, dN); }
    }
    __syncthreads();
    // ===== P9: gi_d2 (768)
    if (tid < 768){
      float gi = mvc<768,32,8>(Wd2ip, (const uint4*)s_di2, tid) + bd2i[tid];
      s_g[tid] = (tid < 512) ? sigm(gi + s_gh2[tid]) : gi;
    }
    __syncthreads();
    // ===== G2 (+ store packed dec_in for the mel post-kernel)
    if (tid < 256){
      float rr = s_g[tid], z = s_g[256+tid];
      float nv = tanhf2(s_g[512+tid] + rr*s_gh2[512+tid]);
      float h  = nv + z*(s_h2f[tid] - nv);
      s_h2f[tid] = h;
      float di = s_dif[tid] + h;
      float hN = __shfl_down(h, 1), dN = __shfl_down(di, 1);
      if (!(tid&1)){
        unsigned dpk = pkh2(di, dN);
        s_h22[tid>>1] = pkh2(h, hN);
        s_di2[tid>>1] = dpk;   // not needed next phase, kept for symmetry
        ((unsigned*)(outMel + (size_t)t*400))[tid>>1] = dpk;
      }
    }
    __syncthreads();
  }
}

// ---------------- launch ----------------
extern "C" void kernel_launch(void* const* d_in, const int* in_sizes, int n_in,
                              void* d_out, int out_size, void* d_ws, size_t ws_size,
                              hipStream_t stream){
  (void)in_sizes; (void)n_in; (void)out_size; (void)ws_size;
  const float* enc    = (const float*)d_in[0];
  const float* inputs = (const float*)d_in[1];
  const float* W1 = (const float*)d_in[2];   const float* b1 = (const float*)d_in[3];
  const float* W2 = (const float*)d_in[4];   const float* b2 = (const float*)d_in[5];
  const float* Wiha = (const float*)d_in[6]; const float* Whha = (const float*)d_in[7];
  const float* biha = (const float*)d_in[8]; const float* bhha = (const float*)d_in[9];
  const float* Wq = (const float*)d_in[10];  const float* v  = (const float*)d_in[11];
  const float* Wm = (const float*)d_in[12];
  const float* Wp = (const float*)d_in[13];  const float* bp = (const float*)d_in[14];
  const float* Wd1i = (const float*)d_in[15]; const float* Wd1h = (const float*)d_in[16];
  const float* bd1i = (const float*)d_in[17]; const float* bd1h = (const float*)d_in[18];
  const float* Wd2i = (const float*)d_in[19]; const float* Wd2h = (const float*)d_in[20];
  const float* bd2i = (const float*)d_in[21]; const float* bd2h = (const float*)d_in[22];
  const float* Wmel = (const float*)d_in[23]; const float* bmel = (const float*)d_in[24];

  char* ws = (char*)d_ws;
  uint4* W1p   = (uint4*)(ws + OFF_W1);
  uint4* W2p   = (uint4*)(ws + OFF_W2);
  uint4* Wihap = (uint4*)(ws + OFF_WIHA);
  uint4* Whhap = (uint4*)(ws + OFF_WHHA);
  uint4* Wqp   = (uint4*)(ws + OFF_WQ);
  uint4* Wpp   = (uint4*)(ws + OFF_WP);
  uint4* Wd1ip = (uint4*)(ws + OFF_WD1I);
  uint4* Wd1hp = (uint4*)(ws + OFF_WD1H);
  uint4* Wd2ip = (uint4*)(ws + OFF_WD2I);
  uint4* Wd2hp = (uint4*)(ws + OFF_WD2H);
  uint4* Wmelp = (uint4*)(ws + OFF_WMEL);
  uint4* Wmp   = (uint4*)(ws + OFF_WM);
  unsigned* tpm  = (unsigned*)(ws + OFF_TPM);
  unsigned* encH = (unsigned*)(ws + OFF_ENCH);

  auto P = [&](const float* s, uint4* dst, int N, int K){
    int k8 = K/8, tot = N*k8;
    pack_w<<<(tot+255)/256, 256, 0, stream>>>(s, dst, N, k8);
  };
  P(W1, W1p, 256, 400);   P(W2, W2p, 128, 256);
  P(Wiha, Wihap, 768, 384); P(Whha, Whhap, 768, 256);
  P(Wq, Wqp, 256, 256);   P(Wm, Wmp, 256, 256);
  P(Wp, Wpp, 256, 512);
  P(Wd1i, Wd1ip, 768, 256); P(Wd1h, Wd1hp, 768, 256);
  P(Wd2i, Wd2ip, 768, 256); P(Wd2h, Wd2hp, 768, 256);
  P(Wmel, Wmelp, 400, 256);

  conv_enc<<<32768, 256, 0, stream>>>(enc, encH);
  pm_kernel<<<dim3(128,128), 1024, 0, stream>>>(enc, Wmp, tpm);
  prenet_kernel<<<dim3(200,128), 256, 0, stream>>>(inputs, b1, b2, W1p, W2p, (float*)d_out);

  decoder<<<128, 1024, 0, stream>>>(
      biha, bhha, v, bp, bd1i, bd1h, bd2i, bd2h,
      Wihap, Whhap, Wqp, Wpp, Wd1ip, Wd1hp, Wd2ip, Wd2hp,
      tpm, encH, (float*)d_out);

  mel_kernel<<<dim3(200,128), 512, 0, stream>>>(bmel, Wmelp, (float*)d_out);
}